// Round 8
// baseline (800.633 us; speedup 1.0000x reference)
//
#include <hip/hip_runtime.h>
#include <cmath>

typedef __bf16 bf16;
typedef __bf16 bf16x2 __attribute__((ext_vector_type(2)));
typedef __bf16 bf16x4 __attribute__((ext_vector_type(4)));
typedef __bf16 bf16x8 __attribute__((ext_vector_type(8)));
typedef float  f32x4  __attribute__((ext_vector_type(4)));

#define AS1(p) ((const __attribute__((address_space(1))) void*)(p))
#define AS3(p) ((__attribute__((address_space(3))) void*)(p))

// problem constants
constexpr int Bc = 2, Tc = 4096, Dc = 1024, Hc = 16, Fc = 4096, Kc = 2048;

// ---------------------------------------------------------------- router (fp32) + init fused
__global__ __launch_bounds__(256) void router_kernel(const float* __restrict__ x,
    const float* __restrict__ rw, const float* __restrict__ rb, float* __restrict__ logits,
    int* __restrict__ slot, int* __restrict__ sel, float* __restrict__ gate){
  int flat = blockIdx.x * 256 + threadIdx.x;       // grid 2048 -> 524288
  if (flat < Bc * Tc) slot[flat] = -1;             // defensive init (no poison survives)
  if (flat < Bc * Kc){ sel[flat] = flat & (Kc - 1); gate[flat] = 0.f; }
  int wv = threadIdx.x >> 6, lane = threadIdx.x & 63;
  int token = blockIdx.x * 4 + wv;                 // 8192 tokens
  const float* xr = x + (size_t)token * Dc;
  float s = 0.f;
#pragma unroll
  for (int i = 0; i < 16; i++){ int d = lane + i*64; s += xr[d] * rw[d]; }
#pragma unroll
  for (int m = 32; m; m >>= 1) s += __shfl_xor(s, m);
  if (lane == 0) logits[token] = s + rb[0];
}

// ---------------------------------------------------------------- top-k by rank counting (parallelized)
__global__ __launch_bounds__(256) void topk_kernel(const float* __restrict__ logits,
    int* __restrict__ slot, int* __restrict__ sel, float* __restrict__ gate){
  __shared__ float lg[Tc];
  int b = blockIdx.x >> 7, seg = blockIdx.x & 127;  // grid 256
  const float* lb = logits + (size_t)b * Tc;
#pragma unroll
  for (int i = 0; i < 4; i++)
    *(float4*)&lg[(threadIdx.x + i*256)*4] = *(const float4*)&lb[(threadIdx.x + i*256)*4];
  __syncthreads();
  int t = seg * 32 + (threadIdx.x >> 3);            // this 8-lane group's token
  int c = threadIdx.x & 7;                           // chunk id within the scan
  float v = lg[t];
  int rank = 0;
#pragma unroll 4
  for (int j4 = c*128; j4 < c*128 + 128; j4++){
    float4 u4 = *(const float4*)&lg[j4*4];
    int j = j4*4;
    rank += (u4.x > v) || (u4.x == v && (j+0) < t);
    rank += (u4.y > v) || (u4.y == v && (j+1) < t);
    rank += (u4.z > v) || (u4.z == v && (j+2) < t);
    rank += (u4.w > v) || (u4.w == v && (j+3) < t);
  }
  rank += __shfl_xor(rank, 1);                       // 8-lane groups are wave-contiguous
  rank += __shfl_xor(rank, 2);
  rank += __shfl_xor(rank, 4);
  if (c == 0 && rank < Kc){
    sel [b*Kc + rank] = t;
    gate[b*Kc + rank] = 1.f / (1.f + expf(-v));
    slot[b*Tc + t] = rank;
  }
}

// ---------------------------------------------------------------- gather to fp32 h
__global__ __launch_bounds__(256) void gather_kernel(const float* __restrict__ x,
    const int* __restrict__ sel, float* __restrict__ h){
  int row = blockIdx.x;                            // b*Kc + k, grid 4096
  int b = row >> 11;
  int t = sel[row];
  t = (t < 0) ? 0 : (t >= Tc ? Tc - 1 : t);        // clamp: fault -> wrong answer
  const float* xr = x + ((size_t)b * Tc + t) * Dc;
  float* hr = h + (size_t)row * Dc;
  int d = threadIdx.x * 4;
  *(float4*)(hr + d) = *(const float4*)(xr + d);
}

// ---------------------------------------------------------------- layernorm fp32->bf16
__global__ __launch_bounds__(256) void ln_kernel(const float* __restrict__ h,
    const float* __restrict__ w, const float* __restrict__ bb, bf16* __restrict__ y){
  __shared__ float red[4], red2[4];
  int row = blockIdx.x, t = threadIdx.x;
  int wv = t >> 6, lane = t & 63;
  const float* hr = h + (size_t)row * Dc;
  float4 x4 = *(const float4*)(hr + t*4);
  float s = x4.x + x4.y + x4.z + x4.w;
#pragma unroll
  for (int m = 32; m; m >>= 1) s += __shfl_xor(s, m);
  if (lane == 0) red[wv] = s;
  __syncthreads();
  float mu = (red[0]+red[1]+red[2]+red[3]) * (1.f/Dc);
  float d0 = x4.x-mu, d1 = x4.y-mu, d2 = x4.z-mu, d3 = x4.w-mu;
  float q = d0*d0 + d1*d1 + d2*d2 + d3*d3;
#pragma unroll
  for (int m = 32; m; m >>= 1) q += __shfl_xor(q, m);
  if (lane == 0) red2[wv] = q;
  __syncthreads();
  float var = (red2[0]+red2[1]+red2[2]+red2[3]) * (1.f/Dc);
  float rs = rsqrtf(var + 1e-5f);
  bf16* yr = y + (size_t)row * Dc;
  int d = t * 4;
  float xv[4] = {x4.x, x4.y, x4.z, x4.w};
#pragma unroll
  for (int i = 0; i < 4; i++)
    yr[d+i] = (bf16)((xv[i]-mu) * rs * w[d+i] + bb[d+i]);
}

// ---------------------------------------------------------------- weight transpose fp32 -> bf16 (tile body)
__device__ __forceinline__ void transpose_tile(const float* __restrict__ in,
    bf16* __restrict__ out, int R, int C, int bx, int by, bf16 (*tile)[72]){
  int c0 = bx * 64, r0 = by * 64;
  int t = threadIdx.x;
#pragma unroll
  for (int i = 0; i < 2; i++){
    int ch = t + i*256;
    int row = ch >> 3, col8 = (ch & 7) * 8;
    const float* src = in + (size_t)(r0+row)*C + c0 + col8;
    float4 a = *(const float4*)src;
    float4 b = *(const float4*)(src + 4);
    bf16x8 v;
    v[0]=(bf16)a.x; v[1]=(bf16)a.y; v[2]=(bf16)a.z; v[3]=(bf16)a.w;
    v[4]=(bf16)b.x; v[5]=(bf16)b.y; v[6]=(bf16)b.z; v[7]=(bf16)b.w;
    *(bf16x8*)&tile[row][col8] = v;
  }
  __syncthreads();
#pragma unroll
  for (int i = 0; i < 2; i++){
    int ch = t + i*256;
    int orow = ch >> 3, oc8 = (ch & 7) * 8;
    bf16x8 v;
#pragma unroll
    for (int j = 0; j < 8; j++) v[j] = tile[oc8+j][orow];
    *(bf16x8*)(out + (size_t)(c0+orow)*R + r0 + oc8) = v;
  }
}

// all 4 per-layer weight transposes in one launch (grid 3072)
__global__ __launch_bounds__(256) void transpose4_kernel(
    const float* __restrict__ wqkv, const float* __restrict__ wo,
    const float* __restrict__ w1,   const float* __restrict__ w2,
    bf16* __restrict__ wqkvT, bf16* __restrict__ woT,
    bf16* __restrict__ w1T,   bf16* __restrict__ w2T){
  __shared__ __attribute__((aligned(16))) bf16 tile[64][72];
  int id = blockIdx.x;
  if (id < 768)        transpose_tile(wqkv, wqkvT, Dc, 3*Dc, id % 48,        id / 48,        tile);
  else if (id < 1024){ int t = id - 768;  transpose_tile(wo, woT, Dc, Dc,   t % 16,         t / 16,         tile); }
  else if (id < 2048){ int t = id - 1024; transpose_tile(w1, w1T, Dc, Fc,   t % 64,         t / 64,         tile); }
  else               { int t = id - 2048; transpose_tile(w2, w2T, Fc, Dc,   t % 16,         t / 16,         tile); }
}

// fast gelu (tanh approx == sigmoid form), exp2-based
__device__ __forceinline__ float fast_gelu(float v){
  float u = exp2f(v * (1.f + 0.044715f*v*v) * -2.30220772f);  // 2*0.79788456*log2(e)
  return v * __builtin_amdgcn_rcpf(1.f + u);
}

// XCD-aware bijective bid remap (T1): valid when nwg % 8 == 0 (all our grids are)
__device__ __forceinline__ int xcd_swizzle(int id, int nwg){
  return (id & 7) * (nwg >> 3) + (id >> 3);
}

// ---------------------------------------------------------------- MFMA GEMM 128x128, BK=64 (+T1 swizzle)
__global__ __launch_bounds__(256) void gemm_bt_kernel(
    const bf16* __restrict__ A, const bf16* __restrict__ Bt,
    bf16* __restrict__ Cbf, float* __restrict__ Cf,
    int M, int N, int Kd, int mode)
{
  __shared__ __attribute__((aligned(16))) bf16 As[128*64];
  __shared__ __attribute__((aligned(16))) bf16 Bs[128*64];
  const int tid = threadIdx.x;
  const int wv = tid >> 6, lane = tid & 63;
  const int wm = wv & 1, wn = wv >> 1;
  const int quad = lane >> 4, l15 = lane & 15;
  const int nwg = gridDim.x * gridDim.y;
  const int bid = xcd_swizzle(blockIdx.y * gridDim.x + blockIdx.x, nwg);
  const int m0 = (bid / gridDim.x) * 128, n0 = (bid % gridDim.x) * 128;
  f32x4 acc[4][4] = {};

  const int arow = tid >> 3;
  const int acol = ((tid & 7) ^ (arow & 7)) * 8;
  const bf16* Ag = A  + (size_t)(m0 + arow) * Kd + acol;
  const bf16* Bg = Bt + (size_t)(n0 + arow) * Kd + acol;
  char* AsB = (char*)As;
  char* BsB = (char*)Bs;
  const size_t rstep = (size_t)32 * Kd;

  const bf16* Ab = As + (size_t)(wm*64 + l15) * 64;
  const bf16* Bb = Bs + (size_t)(wn*64 + l15) * 64;
  const int rx = l15 & 7;

  for (int k0 = 0; k0 < Kd; k0 += 64){
    __syncthreads();
#pragma unroll
    for (int i = 0; i < 4; i++){
      __builtin_amdgcn_global_load_lds(AS1(Ag + i*rstep + k0), AS3(AsB + i*4096 + wv*1024), 16, 0, 0);
      __builtin_amdgcn_global_load_lds(AS1(Bg + i*rstep + k0), AS3(BsB + i*4096 + wv*1024), 16, 0, 0);
    }
    __syncthreads();
#pragma unroll
    for (int s = 0; s < 2; s++){
      const int ax = ((s*4 + quad) ^ rx) * 8;
      bf16x8 af[4], bfr[4];
#pragma unroll
      for (int mt = 0; mt < 4; mt++) af[mt]  = *(const bf16x8*)(Ab + mt*1024 + ax);
#pragma unroll
      for (int nt = 0; nt < 4; nt++) bfr[nt] = *(const bf16x8*)(Bb + nt*1024 + ax);
#pragma unroll
      for (int mt = 0; mt < 4; mt++)
#pragma unroll
        for (int nt = 0; nt < 4; nt++)
          acc[mt][nt] = __builtin_amdgcn_mfma_f32_16x16x32_bf16(af[mt], bfr[nt], acc[mt][nt], 0, 0, 0);
    }
  }
#pragma unroll
  for (int mt = 0; mt < 4; mt++){
    int rr0 = m0 + wm*64 + mt*16 + (lane>>4)*4;
#pragma unroll
    for (int nt = 0; nt < 4; nt++){
      int cc = n0 + wn*64 + nt*16 + (lane&15);
#pragma unroll
      for (int r = 0; r < 4; r++){
        float v = acc[mt][nt][r];
        size_t idx = (size_t)(rr0 + r) * N + cc;
        if (mode == 0)      Cbf[idx] = (bf16)v;
        else if (mode == 1) Cf[idx] += v;
        else                Cbf[idx] = (bf16)fast_gelu(v);
      }
    }
  }
}

// ---------------------------------------------------------------- MFMA GEMM 128x64, BK=64 (+T1 swizzle)
// mode 3 (final w2 GEMM): fused residual+gate+scatter (see R6 notes)
__global__ __launch_bounds__(256) void gemm_bt64_kernel(
    const bf16* __restrict__ A, const bf16* __restrict__ Bt,
    bf16* __restrict__ Cbf, float* __restrict__ Cf,
    int M, int N, int Kd, int mode,
    const float* __restrict__ xg, const int* __restrict__ sel,
    const float* __restrict__ gatep, float* __restrict__ outp)
{
  __shared__ __attribute__((aligned(16))) bf16 As[128*64];
  __shared__ __attribute__((aligned(16))) bf16 Bs[64*64];
  const int tid = threadIdx.x;
  const int wv = tid >> 6, lane = tid & 63;
  const int wm = wv >> 1, wn = wv & 1;            // 2x2 waves: wave = 64(m) x 32(n)
  const int quad = lane >> 4, l15 = lane & 15;
  const int nwg = gridDim.x * gridDim.y;
  const int bid = xcd_swizzle(blockIdx.y * gridDim.x + blockIdx.x, nwg);
  const int m0 = (bid / gridDim.x) * 128, n0 = (bid % gridDim.x) * 64;
  f32x4 acc[4][2] = {};

  const int arow = tid >> 3;
  const int acol = ((tid & 7) ^ (arow & 7)) * 8;
  const bf16* Ag = A  + (size_t)(m0 + arow) * Kd + acol;
  const bf16* Bg = Bt + (size_t)(n0 + arow) * Kd + acol;
  char* AsB = (char*)As;
  char* BsB = (char*)Bs;
  const size_t rstep = (size_t)32 * Kd;

  const bf16* Ab = As + (size_t)(wm*64 + l15) * 64;
  const bf16* Bb = Bs + (size_t)(wn*32 + l15) * 64;
  const int rx = l15 & 7;

  for (int k0 = 0; k0 < Kd; k0 += 64){
    __syncthreads();
#pragma unroll
    for (int i = 0; i < 4; i++)
      __builtin_amdgcn_global_load_lds(AS1(Ag + i*rstep + k0), AS3(AsB + i*4096 + wv*1024), 16, 0, 0);
#pragma unroll
    for (int i = 0; i < 2; i++)
      __builtin_amdgcn_global_load_lds(AS1(Bg + i*rstep + k0), AS3(BsB + i*4096 + wv*1024), 16, 0, 0);
    __syncthreads();
#pragma unroll
    for (int s = 0; s < 2; s++){
      const int ax = ((s*4 + quad) ^ rx) * 8;
      bf16x8 af[4], bfr[2];
#pragma unroll
      for (int mt = 0; mt < 4; mt++) af[mt]  = *(const bf16x8*)(Ab + mt*1024 + ax);
#pragma unroll
      for (int nt = 0; nt < 2; nt++) bfr[nt] = *(const bf16x8*)(Bb + nt*1024 + ax);
#pragma unroll
      for (int mt = 0; mt < 4; mt++)
#pragma unroll
        for (int nt = 0; nt < 2; nt++)
          acc[mt][nt] = __builtin_amdgcn_mfma_f32_16x16x32_bf16(af[mt], bfr[nt], acc[mt][nt], 0, 0, 0);
    }
  }
  if (mode == 3){
#pragma unroll
    for (int mt = 0; mt < 4; mt++){
      int rr0 = m0 + wm*64 + mt*16 + quad*4;
#pragma unroll
      for (int r = 0; r < 4; r++){
        int row = rr0 + r;                       // b*Kc + k
        int bb = row >> 11;
        int t  = sel[row];
        t = (t < 0) ? 0 : (t >= Tc ? Tc - 1 : t);
        float g = gatep[row];
        const size_t obase = ((size_t)bb * Tc + t) * (size_t)Dc;
#pragma unroll
        for (int nt = 0; nt < 2; nt++){
          int cc = n0 + wn*32 + nt*16 + l15;
          float hv = Cf[(size_t)row * N + cc] + acc[mt][nt][r];
          outp[obase + cc] = xg[obase + cc] + g * hv;
        }
      }
    }
    return;
  }
#pragma unroll
  for (int mt = 0; mt < 4; mt++){
    int rr0 = m0 + wm*64 + mt*16 + (lane>>4)*4;
#pragma unroll
    for (int nt = 0; nt < 2; nt++){
      int cc = n0 + wn*32 + nt*16 + (lane&15);
#pragma unroll
      for (int r = 0; r < 4; r++){
        float v = acc[mt][nt][r];
        size_t idx = (size_t)(rr0 + r) * N + cc;
        if (mode == 0)      Cbf[idx] = (bf16)v;
        else if (mode == 1) Cf[idx] += v;
        else                Cbf[idx] = (bf16)fast_gelu(v);
      }
    }
  }
}

// ---------------------------------------------------------------- flash attention v7: KVBLK 64 -> 128
// v4's proven structure (2 barriers/tile, register prefetch, single buffer, pack-loop Vt)
// with the K/V tile doubled: halves barrier pairs (32->16) and per-row fixed overhead.
// Vt swizzle generalizes: store group vg^j^vsw (4-bit; pair-B at (vg+8)^j^vsw), read
// group (s*4+quad)^sw -- k = (s*4+quad)*8 + j as the B-frag requires (bijection checked).
__global__ __launch_bounds__(256) void flash_kernel(const bf16* __restrict__ qkv, bf16* __restrict__ o){
  __shared__ __attribute__((aligned(16))) bf16 Ks[128][72];      // 18.0 KB
  __shared__ __attribute__((aligned(16))) bf16 Vt[128*64];       // 16 KB (layout d*128 + slot)
  __shared__ __attribute__((aligned(16))) bf16 Pt[4][128][16];   // 16 KB per-wave P^T
  const int tid = threadIdx.x, wv = tid >> 6, lane = tid & 63;
  const int quad = lane >> 4, l15 = lane & 15;
  const int bid = blockIdx.x;
  const int qt = bid & 31, hh = (bid >> 5) & 15, b = bid >> 9;
  const int q0 = qt * 64;
  const size_t base = (size_t)b * Kc * (3*Dc);
  const float SC2 = 0.125f * 1.44269504f;          // 1/sqrt(64) * log2(e)

  const int sp8 = (tid & 7) * 8;                   // d-col group for staging
  const int kr0 = tid >> 3;                        // K staging rows kr0 + {0,32,64,96}
  const int vr0 = (tid >> 3) * 2;                  // V row-pairs (vr0,vr0+1), (vr0+64,vr0+65)
  const int vg = vr0 >> 3, vlo = vr0 & 7, vsw = sp8 >> 3;

  // Q direct to registers (A-frag)
  bf16x8 qf[2];
  {
    const bf16* qr = qkv + base + (size_t)(q0 + wv*16 + l15)*(3*Dc) + hh*64 + quad*8;
    qf[0] = *(const bf16x8*)(qr);
    qf[1] = *(const bf16x8*)(qr + 32);
  }

  // prefetch K/V tile 0
  const bf16* kp[4]; const bf16* vp[4];
#pragma unroll
  for (int i = 0; i < 4; i++)
    kp[i] = qkv + base + (size_t)(kr0 + i*32)*(3*Dc) + Dc + hh*64 + sp8;
  vp[0] = qkv + base + (size_t)(vr0     )*(3*Dc) + 2*Dc + hh*64 + sp8;
  vp[1] = vp[0] + 3*Dc;
  vp[2] = qkv + base + (size_t)(vr0 + 64)*(3*Dc) + 2*Dc + hh*64 + sp8;
  vp[3] = vp[2] + 3*Dc;
  bf16x8 kpre[4], vpre[4];
#pragma unroll
  for (int i = 0; i < 4; i++){ kpre[i] = *(const bf16x8*)kp[i]; vpre[i] = *(const bf16x8*)vp[i]; }
  const int TSTRIDE = 128 * 3 * Dc;

  // ones B-frag: column 0 of the virtual 5th V tile
  bf16x8 onesf;
#pragma unroll
  for (int j = 0; j < 8; j++) onesf[j] = (bf16)(l15 == 0 ? 1.f : 0.f);

  f32x4 oacc[4] = {};
  f32x4 oacc5 = {};                                 // row-sums of P (alpha-chained)
  float mrow[4];
#pragma unroll
  for (int r = 0; r < 4; r++) mrow[r] = -1e30f;

  for (int kt = 0; kt < 16; kt++){
    __syncthreads();                               // prev tile's readers done
    // stage K (4x b128) and V (packed kv-pairs, b32, two pair-sets)
#pragma unroll
    for (int i = 0; i < 4; i++)
      *(bf16x8*)&Ks[kr0 + i*32][sp8] = kpre[i];
#pragma unroll
    for (int j = 0; j < 8; j++){
      bf16x2 pa; pa[0] = vpre[0][j]; pa[1] = vpre[1][j];
      bf16x2 pb; pb[0] = vpre[2][j]; pb[1] = vpre[3][j];
      *(bf16x2*)&Vt[(sp8 + j)*128 + (((vg    ) ^ j ^ vsw) << 3) + vlo] = pa;
      *(bf16x2*)&Vt[(sp8 + j)*128 + (((vg + 8) ^ j ^ vsw) << 3) + vlo] = pb;
    }
    __syncthreads();
    // prefetch next tile (overlaps compute below)
    if (kt < 15){
#pragma unroll
      for (int i = 0; i < 4; i++){
        kp[i] += TSTRIDE; vp[i] += TSTRIDE;
        kpre[i] = *(const bf16x8*)kp[i];
        vpre[i] = *(const bf16x8*)vp[i];
      }
    }
    // S = Q K^T over 128 k-rows
    f32x4 sacc[8] = {};
    __builtin_amdgcn_s_setprio(1);
#pragma unroll
    for (int nt = 0; nt < 8; nt++)
#pragma unroll
      for (int s = 0; s < 2; s++){
        bf16x8 kf = *(const bf16x8*)&Ks[nt*16 + l15][s*32 + quad*8];
        sacc[nt] = __builtin_amdgcn_mfma_f32_16x16x32_bf16(qf[s], kf, sacc[nt], 0, 0, 0);
      }
    __builtin_amdgcn_s_setprio(0);
    // ---- online softmax, exp2 domain, deferred rescale (THR = 8) ----
    float lm[4];
#pragma unroll
    for (int r = 0; r < 4; r++){
      float m0 = fmaxf(fmaxf(sacc[0][r], sacc[1][r]), fmaxf(sacc[2][r], sacc[3][r]));
      float m1 = fmaxf(fmaxf(sacc[4][r], sacc[5][r]), fmaxf(sacc[6][r], sacc[7][r]));
      lm[r] = fmaxf(m0, m1);
    }
    bool ok = true;
#pragma unroll
    for (int r = 0; r < 4; r++) ok = ok && (lm[r] * SC2 <= mrow[r] + 8.f);
    if (!__all((int)ok)){
      // slow path: full 16-lane max reduce + alpha rescale (tile 0 + rare growth)
#pragma unroll
      for (int r = 0; r < 4; r++){
        float mx = lm[r];
#pragma unroll
        for (int m = 1; m < 16; m <<= 1) mx = fmaxf(mx, __shfl_xor(mx, m));
        float nm = fmaxf(mrow[r], mx * SC2);
        float alpha = exp2f(mrow[r] - nm);
        mrow[r] = nm;
#pragma unroll
        for (int nt = 0; nt < 4; nt++) oacc[nt][r] *= alpha;
        oacc5[r] *= alpha;
      }
    }
    // P = exp2(S*SC2 - mrow), stored transposed: Pt[wv][k][q], b64 packed stores
#pragma unroll
    for (int nt = 0; nt < 8; nt++){
      bf16x4 w;
#pragma unroll
      for (int r = 0; r < 4; r++) w[r] = (bf16)exp2f(fmaf(sacc[nt][r], SC2, -mrow[r]));
      *(bf16x4*)&Pt[wv][nt*16 + l15][quad*4] = w;
    }
    // P A-frags via HW transpose read: pf[s][j] = Pt[wv][s*32+quad*8+j][l15], s=0..3
    bf16x8 pf[4];
    {
      bf16x4 tlo[4], thi[4];
#pragma unroll
      for (int s = 0; s < 4; s++){
        const bf16* pr = &Pt[wv][s*32 + quad*8][l15];
        asm volatile("ds_read_b64_tr_b16 %0, %1"            : "=v"(tlo[s]) : "v"(AS3(pr)) : "memory");
        asm volatile("ds_read_b64_tr_b16 %0, %1 offset:128" : "=v"(thi[s]) : "v"(AS3(pr)) : "memory");
      }
      asm volatile("s_waitcnt lgkmcnt(0)" ::: "memory");   // rule #18 fence
      __builtin_amdgcn_sched_barrier(0);
#pragma unroll
      for (int s = 0; s < 4; s++)
#pragma unroll
        for (int j = 0; j < 4; j++){
          pf[s][j] = tlo[s][j]; pf[s][j+4] = thi[s][j];
        }
    }
    // PV with swizzled Vt reads + ones-column row-sum (4 k-slices)
    __builtin_amdgcn_s_setprio(1);
#pragma unroll
    for (int nt = 0; nt < 4; nt++){
      int d = nt*16 + l15;
      int sw = (d & 7) ^ ((d >> 3) & 7);
#pragma unroll
      for (int s = 0; s < 4; s++){
        bf16x8 vf = *(const bf16x8*)&Vt[d*128 + (((s*4 + quad) ^ sw) << 3)];
        oacc[nt] = __builtin_amdgcn_mfma_f32_16x16x32_bf16(pf[s], vf, oacc[nt], 0, 0, 0);
      }
    }
#pragma unroll
    for (int s = 0; s < 4; s++)
      oacc5 = __builtin_amdgcn_mfma_f32_16x16x32_bf16(pf[s], onesf, oacc5, 0, 0, 0);
    __builtin_amdgcn_s_setprio(0);
  }
  // epilogue: l lives in lane (quad*16 + 0) of each quad-group, col 0
#pragma unroll
  for (int r = 0; r < 4; r++){
    float l = __shfl(oacc5[r], lane & 48);
    float inv = __builtin_amdgcn_rcpf(l);
    int row = q0 + wv*16 + quad*4 + r;
#pragma unroll
    for (int nt = 0; nt < 4; nt++)
      o[((size_t)b*Kc + row)*Dc + hh*64 + nt*16 + l15] = (bf16)(oacc[nt][r] * inv);
  }
}

// ---------------------------------------------------------------- scatter: unselected rows only
__global__ __launch_bounds__(256) void scatter_kernel(const float* __restrict__ x,
    const int* __restrict__ slot, float* __restrict__ out){
  int row = blockIdx.x;                       // b*Tc + t, grid 8192
  int sl = slot[row];
  if (sl >= 0 && sl < Kc) return;             // written by gemm_bt64 mode 3
  int d = threadIdx.x * 4;
  const float* xr = x + (size_t)row * Dc;
  float* orow = out + (size_t)row * Dc;
  *(float4*)(orow + d) = *(const float4*)(xr + d);
}

// ---------------------------------------------------------------- launch
extern "C" void kernel_launch(void* const* d_in, const int* in_sizes, int n_in,
                              void* d_out, int out_size, void* d_ws, size_t ws_size,
                              hipStream_t stream)
{
  const float* x        = (const float*)d_in[0];
  const float* router_w = (const float*)d_in[1];
  const float* router_b = (const float*)d_in[2];
  const float* ln1_w    = (const float*)d_in[3];
  const float* ln1_b    = (const float*)d_in[4];
  const float* wqkv     = (const float*)d_in[5];
  const float* wo       = (const float*)d_in[6];
  const float* ln2_w    = (const float*)d_in[7];
  const float* ln2_b    = (const float*)d_in[8];
  const float* w1       = (const float*)d_in[9];
  const float* w2       = (const float*)d_in[10];
  float* out = (float*)d_out;

  // workspace layout (bytes), 4 KB pad between regions
  char* ws = (char*)d_ws;
  if (ws_size < 84029440u) return;
  float* logits = (float*)(ws + 0);            //  32768
  int*   slot   = (int*)  (ws + 36864);        //  32768
  int*   sel    = (int*)  (ws + 73728);        //  16384
  float* gate   = (float*)(ws + 94208);        //  16384
  float* h      = (float*)(ws + 114688);       //  16 MB fp32 residual stream [4096,1024]
  bf16*  y      = (bf16*) (ws + 16896000);     //  8 MB  (aliases attention output o)
  bf16*  big    = (bf16*) (ws + 25288704);     //  32 MB (qkv [4096,3072] / gelu [4096,4096])
  bf16*  wqkvT  = (bf16*) (ws + 58847232);     //  6 MB
  bf16*  woT    = (bf16*) (ws + 65142784);     //  2 MB
  bf16*  w1T    = (bf16*) (ws + 67244032);     //  8 MB
  bf16*  w2T    = (bf16*) (ws + 75636736);     //  8 MB; end = 84025344

  router_kernel<<<2048, 256, 0, stream>>>(x, router_w, router_b, logits, slot, sel, gate);
  topk_kernel<<<256, 256, 0, stream>>>(logits, slot, sel, gate);
  gather_kernel<<<4096, 256, 0, stream>>>(x, sel, h);

  for (int l = 0; l < 2; l++){
    transpose4_kernel<<<3072, 256, 0, stream>>>(
        wqkv + (size_t)l*Dc*3*Dc, wo + (size_t)l*Dc*Dc,
        w1 + (size_t)l*Dc*Fc,     w2 + (size_t)l*Fc*Dc,
        wqkvT, woT, w1T, w2T);

    ln_kernel<<<4096, 256, 0, stream>>>(h, ln1_w + l*Dc, ln1_b + l*Dc, y);
    gemm_bt_kernel<<<dim3(24,32), 256, 0, stream>>>(y, wqkvT, big, nullptr, 4096, 3*Dc, Dc, 0);
    flash_kernel<<<1024, 256, 0, stream>>>(big, y);                       // y now holds attn output o
    gemm_bt64_kernel<<<dim3(16,32), 256, 0, stream>>>(y, woT, nullptr, h, 4096, Dc, Dc, 1,
                                                      nullptr, nullptr, nullptr, nullptr);
    ln_kernel<<<4096, 256, 0, stream>>>(h, ln2_w + l*Dc, ln2_b + l*Dc, y);
    gemm_bt_kernel<<<dim3(32,32), 256, 0, stream>>>(y, w1T, big, nullptr, 4096, Fc, Dc, 2);
    if (l == 0)
      gemm_bt64_kernel<<<dim3(16,32), 256, 0, stream>>>(big, w2T, nullptr, h, 4096, Dc, Fc, 1,
                                                        nullptr, nullptr, nullptr, nullptr);
    else
      gemm_bt64_kernel<<<dim3(16,32), 256, 0, stream>>>(big, w2T, nullptr, h, 4096, Dc, Fc, 3,
                                                        x, sel, gate, out);
  }

  scatter_kernel<<<8192, 256, 0, stream>>>(x, slot, out);
}